// Round 8
// baseline (117.694 us; speedup 1.0000x reference)
//
#include <hip/hip_runtime.h>

#define TPB 512

constexpr int NSEQ = 32768;
constexpr int C0   = 4096;               // output samples per chunk; block handles 2 chunks
constexpr float SCG = 14.4269504089f;    // 10 * log2(e)

// Halos {221,109,53,25,11,4}; P = {2296,1144,568,280,136}; E/O halves {1148,572,284,140};
// L5 contiguous stride 136; synth Sout {264,520,1032,2056}; final 4096.
//
// R8: TWO-CHUNK SOFTWARE PIPELINE. Block processes chunks A=2p, B=2p+1 with B one
// phase behind A. Each body = A.phase[k] ∥ B.phase[k-1], written as
// [A-loads; B-loads; A-compute; B-compute]: two INDEPENDENT dependency streams per
// wave -> in-order issue puts all ds_reads first, counted lgkmcnt lets A-compute
// overlap B's outstanding reads (intra-wave LDS||VALU overlap, the thing R6/R7's
// homogeneous bodies could not produce). Barriers: 11 per 2 chunks (vs 11 per 1).
// B.stage global loads are register-split (issue early, ds_write after A.L1) so
// HBM latency hides under compute.
//
// Per chunk ping-pong (X0/X1): stage->0, L1 0->1, L2 1->0, L3 0->1, L4 1->0,
// L5 0->1, s5 1->0, s4 0->1, s3 1->0, s2 0->1, final 1->global.
// LDS: 4 x 4608 x 4B = 73728 B + bss -> 2 blocks/CU, 16 waves/CU.
// Grid = nbatch*4 = 512 = 2 x 256 CUs: one residency generation.

typedef float f2 __attribute__((ext_vector_type(2)));

__device__ __forceinline__ f2 sp(float x) { return (f2){x, x}; }
__device__ __forceinline__ f2 fma2(f2 a, f2 b, f2 c) { return __builtin_elementwise_fma(a, b, c); }

__device__ __forceinline__ float4 ldf4(const float* p) { return *reinterpret_cast<const float4*>(p); }
__device__ __forceinline__ void   stf4(float* p, const float4 v) { *reinterpret_cast<float4*>(p) = v; }

__device__ __forceinline__ void ld12(float* d, const float* p) {
    reinterpret_cast<float4*>(d)[0] = ldf4(p);
    reinterpret_cast<float4*>(d)[1] = ldf4(p + 4);
    reinterpret_cast<float4*>(d)[2] = ldf4(p + 8);
}
__device__ __forceinline__ void ld8(float* d, const float* p) {
    reinterpret_cast<float4*>(d)[0] = ldf4(p);
    reinterpret_cast<float4*>(d)[1] = ldf4(p + 4);
}

__device__ __forceinline__ float rfl(float x) {
    return __builtin_bit_cast(float, __builtin_amdgcn_readfirstlane(__builtin_bit_cast(int, x)));
}

// Packed gate: y * (sigmoid(10(y-b)) + sigmoid(-10(y+b))) on both halves; tb = SCG*b.
__device__ __forceinline__ f2 gated2(f2 y, f2 tb) {
    f2 t1 = fma2(y, sp(-SCG), tb);
    f2 t2 = fma2(y, sp( SCG), tb);
    f2 s;
    s[0] = __builtin_amdgcn_rcpf(1.f + __builtin_amdgcn_exp2f(t1[0]))
         + __builtin_amdgcn_rcpf(1.f + __builtin_amdgcn_exp2f(t2[0]));
    s[1] = __builtin_amdgcn_rcpf(1.f + __builtin_amdgcn_exp2f(t1[1]))
         + __builtin_amdgcn_rcpf(1.f + __builtin_amdgcn_exp2f(t2[1]));
    return y * s;
}

// ---------- per-task pieces (load / compute+store split) ----------

template<int LEin, int TPC>
__device__ __forceinline__ void ana_ld(const float* in, int task, float* a, float* b) {
    const int c  = task / TPC;
    const int i0 = (task - c * TPC) * 8;
    const float* pe = in + c * (2 * LEin) + i0;
    ld12(a, pe);
    ld12(b, pe + LEin);
}

// Compute+store one analysis task (inputs in registers).
template<int Nlev, bool EDGE, int OUTSTRIDE, int EOOFF, bool LAST>
__device__ __forceinline__ void analysis_cs(
    const float* __restrict__ a, const float* __restrict__ b, int c, int i0,
    float* __restrict__ out, const f2* __restrict__ klh,
    const float* __restrict__ bias, int outBase)
{
    const int sw    = c & 1;
    const int ch_lp = 2 * c + sw;
    const int ch_hp = 2 * c + 1 - sw;
    const f2  tb    = (f2){bias[ch_lp], bias[ch_hp]};

    if (LAST) {
        f2 v[8];
#pragma unroll
        for (int r = 0; r < 8; ++r) {
            f2 y = (f2){0.f, 0.f};
#pragma unroll
            for (int u = 0; u < 4; ++u) {
                y = fma2(sp(a[r + u]), klh[2 * u], y);
                y = fma2(sp(b[r + u]), klh[2 * u + 1], y);
            }
            y = gated2(y, tb);
            if (EDGE) {
                const bool ok = ((unsigned)(outBase + i0 + r) < (unsigned)Nlev);
                y[0] = ok ? y[0] : 0.f;
                y[1] = ok ? y[1] : 0.f;
            }
            v[r] = y;
        }
        float* ol = out + ch_lp * OUTSTRIDE + i0;
        float* oh = out + ch_hp * OUTSTRIDE + i0;
        stf4(ol,     make_float4(v[0][0], v[1][0], v[2][0], v[3][0]));
        stf4(ol + 4, make_float4(v[4][0], v[5][0], v[6][0], v[7][0]));
        stf4(oh,     make_float4(v[0][1], v[1][1], v[2][1], v[3][1]));
        stf4(oh + 4, make_float4(v[4][1], v[5][1], v[6][1], v[7][1]));
    } else {
        const int j0 = i0 >> 1;
        float* ol = out + ch_lp * OUTSTRIDE + j0;
        float* oh = out + ch_hp * OUTSTRIDE + j0;
#pragma unroll
        for (int par = 0; par < 2; ++par) {            // par=0 -> E plane, par=1 -> O plane
            f2 w[4];
#pragma unroll
            for (int k = 0; k < 4; ++k) {
                const int r = 2 * k + par;
                f2 y = (f2){0.f, 0.f};
#pragma unroll
                for (int u = 0; u < 4; ++u) {
                    y = fma2(sp(a[r + u]), klh[2 * u], y);
                    y = fma2(sp(b[r + u]), klh[2 * u + 1], y);
                }
                y = gated2(y, tb);
                if (EDGE) {
                    const bool ok = ((unsigned)(outBase + i0 + r) < (unsigned)Nlev);
                    y[0] = ok ? y[0] : 0.f;
                    y[1] = ok ? y[1] : 0.f;
                }
                w[k] = y;
            }
            stf4(ol + par * EOOFF, make_float4(w[0][0], w[1][0], w[2][0], w[3][0]));
            stf4(oh + par * EOOFF, make_float4(w[0][1], w[1][1], w[2][1], w[3][1]));
        }
    }
}

template<int TPC, int Nlev, bool EDGE, int OS, int EO, bool LAST>
__device__ __forceinline__ void ana_do(const float* a, const float* b, int task,
    float* out, const f2* klh, const float* bias, int outBase)
{
    const int c  = task / TPC;
    const int i0 = (task - c * TPC) * 8;
    analysis_cs<Nlev, EDGE, OS, EO, LAST>(a, b, c, i0, out, klh, bias, outBase);
}

template<int INSTRIDE, int TPG>
__device__ __forceinline__ void syn_ld(const float* in, int task, float* ya, float* yb) {
    const int g   = task / TPG;
    const int nl0 = (task - g * TPG) * 8;
    const int sw  = g & 1;
    ld8(ya, in + (2 * g + sw)     * INSTRIDE + nl0 / 2);
    ld8(yb, in + (2 * g + 1 - sw) * INSTRIDE + nl0 / 2);
}

// Packed synthesis core: 8 outputs; lrev[q]=(lp[6-2q],lp[7-2q]); hrev likewise.
template<int JROFF, bool EDGE>
__device__ __forceinline__ void synth_core(
    const float* __restrict__ ya, const float* __restrict__ yb,
    const f2* __restrict__ lrev, const f2* __restrict__ hrev,
    int gpos, int Nlev, float* __restrict__ o)
{
    f2 p1 = (f2){0.f, 0.f}, p2 = (f2){0.f, 0.f}, p3 = (f2){0.f, 0.f};
    float o0 = 0.f, o7 = 0.f;
#pragma unroll
    for (int q = 0; q < 4; ++q) {
        const f2 cl = lrev[q], ch = hrev[q];
        o0 = fmaf(ya[JROFF + q],     cl[1], o0);
        o0 = fmaf(yb[JROFF + q],     ch[1], o0);
        o7 = fmaf(ya[JROFF + 4 + q], cl[0], o7);
        o7 = fmaf(yb[JROFF + 4 + q], ch[0], o7);
        p1 = fma2(sp(ya[JROFF + 1 + q]), cl, p1);
        p1 = fma2(sp(yb[JROFF + 1 + q]), ch, p1);
        p2 = fma2(sp(ya[JROFF + 2 + q]), cl, p2);
        p2 = fma2(sp(yb[JROFF + 2 + q]), ch, p2);
        p3 = fma2(sp(ya[JROFF + 3 + q]), cl, p3);
        p3 = fma2(sp(yb[JROFF + 3 + q]), ch, p3);
    }
    o[0] = o0;    o[1] = p1[0]; o[2] = p1[1]; o[3] = p2[0];
    o[4] = p2[1]; o[5] = p3[0]; o[6] = p3[1]; o[7] = o7;
    if (EDGE) {
#pragma unroll
        for (int r = 0; r < 8; ++r) {
            const bool ok = ((unsigned)(gpos + r) < (unsigned)Nlev);
            o[r] = ok ? o[r] : 0.f;
        }
    }
}

template<int TPG, int Sout, int Nlev, bool EDGE>
__device__ __forceinline__ void syn_do(const float* ya, const float* yb, int task,
    float* out, const f2* lrev, const f2* hrev, int outBase)
{
    const int g   = task / TPG;
    const int nl0 = (task - g * TPG) * 8;
    float o[8];
    synth_core<0, EDGE>(ya, yb, lrev, hrev, outBase + nl0, Nlev, o);
    float* op = out + g * Sout + nl0;
    stf4(op,     make_float4(o[0], o[1], o[2], o[3]));
    stf4(op + 4, make_float4(o[4], o[5], o[6], o[7]));
}

// ---------- stage (register-split: load early, LDS-write late) ----------
// base = s-221 (==3 mod 4), a0 = base-3 16B-aligned. Quad q -> O[2q-2],E[2q-1],O[2q-1],E[2q].
template<bool EDGE>
__device__ __forceinline__ void stage_ld(const float* __restrict__ xb, int s, float4* v) {
    const int tid = threadIdx.x;
    const int a0  = s - 224;
#pragma unroll
    for (int k = 0; k < 3; ++k) {
        const int q = tid + TPB * k;
        float4 t = make_float4(0.f, 0.f, 0.f, 0.f);
        if (q < 1151) {
            const int a = a0 + 4 * q;
            if (!EDGE || (a >= 0 && a + 3 < NSEQ)) {
                t = ldf4(xb + a);
            } else {
                t.x = ((unsigned)(a)     < (unsigned)NSEQ) ? xb[a]     : 0.f;
                t.y = ((unsigned)(a + 1) < (unsigned)NSEQ) ? xb[a + 1] : 0.f;
                t.z = ((unsigned)(a + 2) < (unsigned)NSEQ) ? xb[a + 2] : 0.f;
                t.w = ((unsigned)(a + 3) < (unsigned)NSEQ) ? xb[a + 3] : 0.f;
            }
        }
        v[k] = t;
    }
}
__device__ __forceinline__ void stage_st(const float4* v, float* __restrict__ buf) {
    const int tid = threadIdx.x;
#pragma unroll
    for (int k = 0; k < 3; ++k) {
        const int q = tid + TPB * k;
        if (q < 1151) {
            const int jo = 2 * q - 2;
            const int je = 2 * q - 1;
            if ((unsigned)jo       < 2300u) buf[2304 + jo]     = v[k].x;
            if ((unsigned)je       < 2300u) buf[je]            = v[k].y;
            if ((unsigned)(jo + 1) < 2300u) buf[2304 + jo + 1] = v[k].z;
            if ((unsigned)(je + 1) < 2300u) buf[je + 1]        = v[k].w;
        }
    }
}

// ---------- paired bodies: loads of BOTH streams first, then computes ----------

template<int LA,int PA,int PRA,int NA,bool EA,int OSA,int EOA,bool LASTA,
         int LB,int PB,int PRB,int NB,bool EB,int OSB,int EOB,bool LASTB>
__device__ __forceinline__ void body_aa(
    const float* Ain, float* Aout, const float* biasA, int obA,
    const float* Bin, float* Bout, const float* biasB, int obB,
    const f2* klh)
{
    const int tid = threadIdx.x;
    constexpr int TPCA = PA / 8, TOTA = PRA * TPCA;
    constexpr int TPCB = PB / 8, TOTB = PRB * TPCB;
    const int tA = tid < TOTA ? tid : TOTA - 1;
    const int tB = tid < TOTB ? tid : TOTB - 1;
    float aA[12], bA[12], aB[12], bB[12];
    ana_ld<LA, TPCA>(Ain, tA, aA, bA);
    ana_ld<LB, TPCB>(Bin, tB, aB, bB);
    if (tid < TOTA) ana_do<TPCA, NA, EA, OSA, EOA, LASTA>(aA, bA, tA, Aout, klh, biasA, obA);
    if (tid < TOTB) ana_do<TPCB, NB, EB, OSB, EOB, LASTB>(aB, bB, tB, Bout, klh, biasB, obB);
    __syncthreads();
}

template<int ISA,int SoA,int GA,int NA,bool EA,
         int LB,int PB,int PRB,int NB,bool EB,int OSB,int EOB,bool LASTB>
__device__ __forceinline__ void body_sa(
    const float* Ain, float* Aout, int obA,
    const float* Bin, float* Bout, const float* biasB, int obB,
    const f2* klh, const f2* lrev, const f2* hrev)
{
    const int tid = threadIdx.x;
    constexpr int TPGA = SoA / 8, TOTA = GA * TPGA;    // 528 > TPB
    constexpr int TPCB = PB / 8, TOTB = PRB * TPCB;    // 272
    const int tB = tid < TOTB ? tid : TOTB - 1;
    float yaA[8], ybA[8], aB[12], bB[12];
    syn_ld<ISA, TPGA>(Ain, tid, yaA, ybA);
    ana_ld<LB, TPCB>(Bin, tB, aB, bB);
    syn_do<TPGA, SoA, NA, EA>(yaA, ybA, tid, Aout, lrev, hrev, obA);
    if (tid < TOTB) ana_do<TPCB, NB, EB, OSB, EOB, LASTB>(aB, bB, tB, Bout, klh, biasB, obB);
    if (tid + TPB < TOTA) {
        const int t = tid + TPB;
        float ya[8], yb[8];
        syn_ld<ISA, TPGA>(Ain, t, ya, yb);
        syn_do<TPGA, SoA, NA, EA>(ya, yb, t, Aout, lrev, hrev, obA);
    }
    __syncthreads();
}

template<int ISA,int SoA,int GA,int NA,bool EA,
         int ISB,int SoB,int GB,int NB,bool EB>
__device__ __forceinline__ void body_ss(
    const float* Ain, float* Aout, int obA,
    const float* Bin, float* Bout, int obB,
    const f2* lrev, const f2* hrev)
{
    const int tid = threadIdx.x;
    constexpr int TPGA = SoA / 8, TOTA = GA * TPGA;
    constexpr int TPGB = SoB / 8, TOTB = GB * TPGB;
    float yaA[8], ybA[8], yaB[8], ybB[8];
    syn_ld<ISA, TPGA>(Ain, tid, yaA, ybA);         // TOT >= 514 -> unconditional
    syn_ld<ISB, TPGB>(Bin, tid, yaB, ybB);
    syn_do<TPGA, SoA, NA, EA>(yaA, ybA, tid, Aout, lrev, hrev, obA);
    syn_do<TPGB, SoB, NB, EB>(yaB, ybB, tid, Bout, lrev, hrev, obB);
    if (tid + TPB < TOTA) {
        const int t = tid + TPB;
        float ya[8], yb[8];
        syn_ld<ISA, TPGA>(Ain, t, ya, yb);
        syn_do<TPGA, SoA, NA, EA>(ya, yb, t, Aout, lrev, hrev, obA);
    }
    if (tid + TPB < TOTB) {
        const int t = tid + TPB;
        float ya[8], yb[8];
        syn_ld<ISB, TPGB>(Bin, t, ya, yb);
        syn_do<TPGB, SoB, NB, EB>(ya, yb, t, Bout, lrev, hrev, obB);
    }
    __syncthreads();
}

template<int ISB,int SoB,int GB,int NB,bool EB>
__device__ __forceinline__ void body_fs(
    const float* Afin, float* oa,
    const float* Bin, float* Bout, int obB,
    const f2* lrev, const f2* hrev)
{
    const int tid = threadIdx.x;
    constexpr int TPGB = SoB / 8, TOTB = GB * TPGB;    // 514
    const int i0 = tid * 8;
    float ya[12], yb[12], yaB[8], ybB[8];
    ld12(ya, Afin + i0 / 2);
    ld12(yb, Afin + i0 / 2 + 2056);
    syn_ld<ISB, TPGB>(Bin, tid, yaB, ybB);
    {
        float o[8];
        synth_core<2, false>(ya, yb, lrev, hrev, 0, 1 << 30, o);
        stf4(oa + i0,     make_float4(o[0], o[1], o[2], o[3]));
        stf4(oa + i0 + 4, make_float4(o[4], o[5], o[6], o[7]));
    }
    syn_do<TPGB, SoB, NB, EB>(yaB, ybB, tid, Bout, lrev, hrev, obB);
    if (tid + TPB < TOTB) {
        const int t = tid + TPB;
        float y2a[8], y2b[8];
        syn_ld<ISB, TPGB>(Bin, t, y2a, y2b);
        syn_do<TPGB, SoB, NB, EB>(y2a, y2b, t, Bout, lrev, hrev, obB);
    }
    __syncthreads();
}

// ---------- two-chunk pipelined driver ----------

template<bool EDGEA, bool EDGEB>
__device__ __forceinline__ void run_pair(
    const float* __restrict__ xb, float* __restrict__ oa, float* __restrict__ ob,
    int sa, int sb,
    float* A0, float* A1, float* B0, float* B1,
    const f2* klh, const f2* lrev, const f2* hrev, const float* bss)
{
    const int tid = threadIdx.x;

    // b0: A.stage -> A0
    {
        float4 v[3];
        stage_ld<EDGEA>(xb, sa, v);
        stage_st(v, A0);
    }
    __syncthreads();

    // b1: A.L1 (A0->A1) ∥ B.stage (->B0); B globals issued first, LDS-written last (T14)
    {
        float4 v[3];
        stage_ld<EDGEB>(xb, sb, v);
        const int tA = tid < 287 ? tid : 286;
        float a[12], b[12];
        ana_ld<2304, 287>(A0, tA, a, b);
        if (tid < 287)
            ana_do<287, 16384, EDGEA, 2296, 1148, false>(a, b, tA, A1, klh, bss + 0, (sa >> 1) - 109);
        stage_st(v, B0);
    }
    __syncthreads();

    // b2: A.L2 (A1->A0) ∥ B.L1 (B0->B1)
    body_aa<1148,1144,2,8192,EDGEA,1144,572,false,
            2304,2296,1,16384,EDGEB,2296,1148,false>(
        A1, A0, bss + 2, (sa >> 2) - 53,
        B0, B1, bss + 0, (sb >> 1) - 109, klh);

    // b3: A.L3 (A0->A1) ∥ B.L2 (B1->B0)
    body_aa<572,568,4,4096,EDGEA,568,284,false,
            1148,1144,2,8192,EDGEB,1144,572,false>(
        A0, A1, bss + 6, (sa >> 3) - 25,
        B1, B0, bss + 2, (sb >> 2) - 53, klh);

    // b4: A.L4 (A1->A0) ∥ B.L3 (B0->B1)
    body_aa<284,280,8,2048,EDGEA,280,140,false,
            572,568,4,4096,EDGEB,568,284,false>(
        A1, A0, bss + 14, (sa >> 4) - 11,
        B0, B1, bss + 6, (sb >> 3) - 25, klh);

    // b5: A.L5 (A0->A1) ∥ B.L4 (B1->B0)
    body_aa<140,136,16,1024,EDGEA,136,0,true,
            284,280,8,2048,EDGEB,280,140,false>(
        A0, A1, bss + 30, (sa >> 5) - 4,
        B1, B0, bss + 14, (sb >> 4) - 11, klh);

    // b6: A.s5 (A1->A0) ∥ B.L5 (B0->B1)
    body_sa<136,264,16,2048,EDGEA,
            140,136,16,1024,EDGEB,136,0,true>(
        A1, A0, (sa >> 4) - 4,
        B0, B1, bss + 30, (sb >> 5) - 4, klh, lrev, hrev);

    // b7: A.s4 (A0->A1) ∥ B.s5 (B1->B0)
    body_ss<264,520,8,4096,EDGEA, 136,264,16,2048,EDGEB>(
        A0, A1, (sa >> 3) - 4, B1, B0, (sb >> 4) - 4, lrev, hrev);

    // b8: A.s3 (A1->A0) ∥ B.s4 (B0->B1)
    body_ss<520,1032,4,8192,EDGEA, 264,520,8,4096,EDGEB>(
        A1, A0, (sa >> 2) - 4, B0, B1, (sb >> 3) - 4, lrev, hrev);

    // b9: A.s2 (A0->A1) ∥ B.s3 (B1->B0)
    body_ss<1032,2056,2,16384,EDGEA, 520,1032,4,8192,EDGEB>(
        A0, A1, (sa >> 1) - 4, B1, B0, (sb >> 2) - 4, lrev, hrev);

    // b10: A.final (A1->oa) ∥ B.s2 (B0->B1)
    body_fs<1032,2056,2,16384,EDGEB>(
        A1, oa, B0, B1, (sb >> 1) - 4, lrev, hrev);

    // b11: B.final (B1->ob)
    {
        const int i0 = tid * 8;
        float ya[12], yb[12];
        ld12(ya, B1 + i0 / 2);
        ld12(yb, B1 + i0 / 2 + 2056);
        float o[8];
        synth_core<2, false>(ya, yb, lrev, hrev, 0, 1 << 30, o);
        stf4(ob + i0,     make_float4(o[0], o[1], o[2], o[3]));
        stf4(ob + i0 + 4, make_float4(o[4], o[5], o[6], o[7]));
    }
}

__global__ __launch_bounds__(TPB, 4) void wpt_fused(
    const float* __restrict__ x,
    const float* __restrict__ K1, const float* __restrict__ K2,
    const float* __restrict__ K3, const float* __restrict__ K4,
    const float* __restrict__ K5,
    const float* __restrict__ B1, const float* __restrict__ B2,
    const float* __restrict__ B3, const float* __restrict__ B4,
    const float* __restrict__ B5,
    float* __restrict__ out)
{
    __shared__ __align__(16) float A0[4608];
    __shared__ __align__(16) float A1[4608];
    __shared__ __align__(16) float Bb0[4608];
    __shared__ __align__(16) float Bb1[4608];
    __shared__ float bss[62];

    const int tid   = threadIdx.x;
    const int batch = blockIdx.x >> 2;
    const int pair  = blockIdx.x & 3;
    const int sa    = pair * (2 * C0);
    const int sb    = sa + C0;

    // Filters in SGPRs: K1 = [lp | hp]; every level's rows are one of these two.
    float lp[8], hp[8];
#pragma unroll
    for (int t = 0; t < 8; ++t) {
        lp[t] = rfl(K1[t]);
        hp[t] = rfl(K1[8 + t]);
    }
    f2 klh[8], lrev[4], hrev[4];
#pragma unroll
    for (int t = 0; t < 8; ++t) klh[t] = (f2){lp[t], hp[t]};
#pragma unroll
    for (int q = 0; q < 4; ++q) {
        lrev[q] = (f2){lp[6 - 2 * q], lp[7 - 2 * q]};
        hrev[q] = (f2){hp[6 - 2 * q], hp[7 - 2 * q]};
    }

    // Biases (pre-scaled by 10*log2(e)); 62 total (covered by b0's barrier)
    {
        const float* bin[5] = {B1, B2, B3, B4, B5};
        const int boff[5] = {0, 2, 6, 14, 30};
#pragma unroll
        for (int l = 0; l < 5; ++l)
            for (int i = tid; i < (2 << l); i += TPB) bss[boff[l] + i] = SCG * bin[l][i];
    }

    const float* xb = x + batch * NSEQ;
    float* oa = out + batch * NSEQ + sa;
    float* ob = oa + C0;

    if (pair == 0)
        run_pair<true,  false>(xb, oa, ob, sa, sb, A0, A1, Bb0, Bb1, klh, lrev, hrev, bss);
    else if (pair == 3)
        run_pair<false, true >(xb, oa, ob, sa, sb, A0, A1, Bb0, Bb1, klh, lrev, hrev, bss);
    else
        run_pair<false, false>(xb, oa, ob, sa, sb, A0, A1, Bb0, Bb1, klh, lrev, hrev, bss);
}

extern "C" void kernel_launch(void* const* d_in, const int* in_sizes, int n_in,
                              void* d_out, int out_size, void* d_ws, size_t ws_size,
                              hipStream_t stream) {
    const int nbatch = in_sizes[0] / NSEQ;
    wpt_fused<<<dim3(nbatch * 4), dim3(TPB), 0, stream>>>(
        (const float*)d_in[0],
        (const float*)d_in[1], (const float*)d_in[2],
        (const float*)d_in[3], (const float*)d_in[4],
        (const float*)d_in[5],
        (const float*)d_in[6], (const float*)d_in[7],
        (const float*)d_in[8], (const float*)d_in[9],
        (const float*)d_in[10],
        (float*)d_out);
}

// Round 9
// 115.058 us; speedup vs baseline: 1.0229x; 1.0229x over previous
//
#include <hip/hip_runtime.h>

#define TPB 256

constexpr int NSEQ = 32768;
constexpr int C0   = 4096;               // output samples per block chunk (8 chunks/batch)
constexpr float SCG = 14.4269504089f;    // 10 * log2(e)

// Halos h_l = 2*h_{l+1}+3, h5=4 -> {221,109,53,25,11,4}
// Geometry: P5 = C0/32 + 8, P_{l-1} = 2*P_l + 8.
// C0=4096 padded level widths P: {2296,1144,568,280,136}; E/O halves {1148,572,284,140};
// L5 out contiguous stride 136; synthesis Sout {264,520,1032,2056}; final 4096.
//
// R9 = R7 (best) minus the stage phase: L1 reads x DIRECTLY from global.
// Window per L1 task: w[0..27] at a0 = s-224+16*task (16B-aligned: s mult of 4096),
// E[u]=w[3+2u], O[u]=w[4+2u] — deinterleave is register renaming, zero cost.
// Deletes per chunk: ~4.6K scalar ds_writes + ~1.7K thread-b128 ds_reads (~25% of
// LDS inst), one barrier, one load->store->barrier->load dependency link.
// 9 barriers: bss|L1|L2|L3|L4|L5|s5|s4|s3|s2|final.
//
// Ping-pong: L1 glb->B, L2 B->A, L3 A->B, L4 B->A, L5 A->B,
//            s5 B->A, s4 A->B, s3 B->A, s2 A->B, final B->global.
// LDS = (4608+4608+62)*4 = 37112 B -> 4 blocks/CU; 4 waves/block -> 16 waves/CU.
// launch_bounds(256,4) -> 128 VGPR/wave cap.
// Grid = 128 batches * 8 chunks = 1024 blocks = 4 * 256 CUs: one generation.

typedef float f2 __attribute__((ext_vector_type(2)));

__device__ __forceinline__ f2 sp(float x) { return (f2){x, x}; }
__device__ __forceinline__ f2 fma2(f2 a, f2 b, f2 c) { return __builtin_elementwise_fma(a, b, c); }

__device__ __forceinline__ float4 ldf4(const float* p) { return *reinterpret_cast<const float4*>(p); }
__device__ __forceinline__ void   stf4(float* p, const float4 v) { *reinterpret_cast<float4*>(p) = v; }

__device__ __forceinline__ void ld12(float* d, const float* p) {
    reinterpret_cast<float4*>(d)[0] = ldf4(p);
    reinterpret_cast<float4*>(d)[1] = ldf4(p + 4);
    reinterpret_cast<float4*>(d)[2] = ldf4(p + 8);
}
__device__ __forceinline__ void ld8(float* d, const float* p) {
    reinterpret_cast<float4*>(d)[0] = ldf4(p);
    reinterpret_cast<float4*>(d)[1] = ldf4(p + 4);
}

__device__ __forceinline__ float rfl(float x) {
    return __builtin_bit_cast(float, __builtin_amdgcn_readfirstlane(__builtin_bit_cast(int, x)));
}

// Packed gate: y * (sigmoid(10(y-b)) + sigmoid(-10(y+b))) on both halves; tb = SCG*b.
__device__ __forceinline__ f2 gated2(f2 y, f2 tb) {
    f2 t1 = fma2(y, sp(-SCG), tb);
    f2 t2 = fma2(y, sp( SCG), tb);
    f2 s;
    s[0] = __builtin_amdgcn_rcpf(1.f + __builtin_amdgcn_exp2f(t1[0]))
         + __builtin_amdgcn_rcpf(1.f + __builtin_amdgcn_exp2f(t2[0]));
    s[1] = __builtin_amdgcn_rcpf(1.f + __builtin_amdgcn_exp2f(t1[1]))
         + __builtin_amdgcn_rcpf(1.f + __builtin_amdgcn_exp2f(t2[1]));
    return y * s;
}

// Compute+store for one analysis task (inputs already in registers).
template<int Nlev, bool EDGE, int OUTSTRIDE, int EOOFF, bool LAST>
__device__ __forceinline__ void analysis_cs(
    const float* __restrict__ a, const float* __restrict__ b, int c, int i0,
    float* __restrict__ out, const f2* __restrict__ klh,
    const float* __restrict__ bias, int outBase)
{
    const int sw    = c & 1;
    const int ch_lp = 2 * c + sw;
    const int ch_hp = 2 * c + 1 - sw;
    const f2  tb    = (f2){bias[ch_lp], bias[ch_hp]};

    if (LAST) {
        f2 v[8];
#pragma unroll
        for (int r = 0; r < 8; ++r) {
            f2 y = (f2){0.f, 0.f};
#pragma unroll
            for (int u = 0; u < 4; ++u) {
                y = fma2(sp(a[r + u]), klh[2 * u], y);
                y = fma2(sp(b[r + u]), klh[2 * u + 1], y);
            }
            y = gated2(y, tb);
            if (EDGE) {
                const bool ok = ((unsigned)(outBase + i0 + r) < (unsigned)Nlev);
                y[0] = ok ? y[0] : 0.f;
                y[1] = ok ? y[1] : 0.f;
            }
            v[r] = y;
        }
        float* ol = out + ch_lp * OUTSTRIDE + i0;
        float* oh = out + ch_hp * OUTSTRIDE + i0;
        stf4(ol,     make_float4(v[0][0], v[1][0], v[2][0], v[3][0]));
        stf4(ol + 4, make_float4(v[4][0], v[5][0], v[6][0], v[7][0]));
        stf4(oh,     make_float4(v[0][1], v[1][1], v[2][1], v[3][1]));
        stf4(oh + 4, make_float4(v[4][1], v[5][1], v[6][1], v[7][1]));
    } else {
        const int j0 = i0 >> 1;
        float* ol = out + ch_lp * OUTSTRIDE + j0;
        float* oh = out + ch_hp * OUTSTRIDE + j0;
#pragma unroll
        for (int par = 0; par < 2; ++par) {            // par=0 -> E plane, par=1 -> O plane
            f2 w[4];
#pragma unroll
            for (int k = 0; k < 4; ++k) {
                const int r = 2 * k + par;
                f2 y = (f2){0.f, 0.f};
#pragma unroll
                for (int u = 0; u < 4; ++u) {
                    y = fma2(sp(a[r + u]), klh[2 * u], y);
                    y = fma2(sp(b[r + u]), klh[2 * u + 1], y);
                }
                y = gated2(y, tb);
                if (EDGE) {
                    const bool ok = ((unsigned)(outBase + i0 + r) < (unsigned)Nlev);
                    y[0] = ok ? y[0] : 0.f;
                    y[1] = ok ? y[1] : 0.f;
                }
                w[k] = y;
            }
            stf4(ol + par * EOOFF, make_float4(w[0][0], w[1][0], w[2][0], w[3][0]));
            stf4(oh + par * EOOFF, make_float4(w[0][1], w[1][1], w[2][1], w[3][1]));
        }
    }
}

// Dual-task block-wide analysis from LDS (TOT in (TPB, 2*TPB]); loads for BOTH
// tasks issued before either compute.
template<int LEin, int P, int PAIRS, int Nlev, bool EDGE, int OUTSTRIDE, int EOOFF, bool LAST = false>
__device__ __forceinline__ void analysis8(
    const float* __restrict__ in, float* __restrict__ out,
    const f2* __restrict__ klh, const float* __restrict__ bias, int outBase)
{
    constexpr int TPC = P / 8;
    constexpr int TOT = PAIRS * TPC;
    static_assert(TOT > TPB && TOT <= 2 * TPB, "analysis must be dual-generation");
    const int t0 = threadIdx.x;
    const int t1 = t0 + TPB;
    const bool has1 = (t1 < TOT);

    const int c0 = t0 / TPC, i0 = (t0 - c0 * TPC) * 8;
    const int c1 = t1 / TPC, i1 = (t1 - c1 * TPC) * 8;

    float a0[12], b0[12], a1[12], b1[12];
    {
        const float* pe = in + c0 * (2 * LEin) + i0;
        ld12(a0, pe);
        ld12(b0, pe + LEin);
    }
    if (has1) {
        const float* pe = in + c1 * (2 * LEin) + i1;
        ld12(a1, pe);
        ld12(b1, pe + LEin);
    }
    analysis_cs<Nlev, EDGE, OUTSTRIDE, EOOFF, LAST>(a0, b0, c0, i0, out, klh, bias, outBase);
    if (has1)
        analysis_cs<Nlev, EDGE, OUTSTRIDE, EOOFF, LAST>(a1, b1, c1, i1, out, klh, bias, outBase);
}

// L1 x-window load straight from global: w[0..27] at a0 = s-224+16*task.
// a0 is 16B-aligned (s multiple of 4096). EDGE: per-load bounds fallback.
template<bool EDGE>
__device__ __forceinline__ void l1_ld(const float* __restrict__ xb, int s, int task, float* w) {
    const int a0 = s - 224 + 16 * task;
#pragma unroll
    for (int k = 0; k < 7; ++k) {
        const int a = a0 + 4 * k;
        float4 v;
        if (!EDGE || (a >= 0 && a + 3 < NSEQ)) {
            v = ldf4(xb + a);
        } else {
            v.x = ((unsigned)(a)     < (unsigned)NSEQ) ? xb[a]     : 0.f;
            v.y = ((unsigned)(a + 1) < (unsigned)NSEQ) ? xb[a + 1] : 0.f;
            v.z = ((unsigned)(a + 2) < (unsigned)NSEQ) ? xb[a + 2] : 0.f;
            v.w = ((unsigned)(a + 3) < (unsigned)NSEQ) ? xb[a + 3] : 0.f;
        }
        reinterpret_cast<float4*>(w)[k] = v;
    }
}

// Deinterleave (register renaming) + compute+store one L1 task.
template<bool EDGE>
__device__ __forceinline__ void l1_do(
    const float* __restrict__ w, int task, float* __restrict__ out,
    const f2* __restrict__ klh, const float* __restrict__ bss, int s)
{
    float a[12], b[12];
#pragma unroll
    for (int u = 0; u < 12; ++u) {
        a[u] = w[3 + 2 * u];       // E[i0+u] = x[base+2(i0+u)]
        b[u] = w[4 + 2 * u];       // O[i0+u]
    }
    analysis_cs<16384, EDGE, 2296, 1148, false>(a, b, 0, task * 8, out, klh, bss + 0, (s >> 1) - 109);
}

// Packed synthesis core: 8 outputs from ya/yb windows.
// lrev[q] = (lp[6-2q], lp[7-2q]); hrev[q] = (hp[6-2q], hp[7-2q]).  JROFF: window offset.
template<int JROFF, bool EDGE>
__device__ __forceinline__ void synth_core(
    const float* __restrict__ ya, const float* __restrict__ yb,
    const f2* __restrict__ lrev, const f2* __restrict__ hrev,
    int gpos, int Nlev, float* __restrict__ o)
{
    f2 p1 = (f2){0.f, 0.f}, p2 = (f2){0.f, 0.f}, p3 = (f2){0.f, 0.f};
    float o0 = 0.f, o7 = 0.f;
#pragma unroll
    for (int q = 0; q < 4; ++q) {
        const f2 cl = lrev[q], ch = hrev[q];
        o0 = fmaf(ya[JROFF + q],     cl[1], o0);
        o0 = fmaf(yb[JROFF + q],     ch[1], o0);
        o7 = fmaf(ya[JROFF + 4 + q], cl[0], o7);
        o7 = fmaf(yb[JROFF + 4 + q], ch[0], o7);
        p1 = fma2(sp(ya[JROFF + 1 + q]), cl, p1);
        p1 = fma2(sp(yb[JROFF + 1 + q]), ch, p1);
        p2 = fma2(sp(ya[JROFF + 2 + q]), cl, p2);
        p2 = fma2(sp(yb[JROFF + 2 + q]), ch, p2);
        p3 = fma2(sp(ya[JROFF + 3 + q]), cl, p3);
        p3 = fma2(sp(yb[JROFF + 3 + q]), ch, p3);
    }
    o[0] = o0;    o[1] = p1[0]; o[2] = p1[1]; o[3] = p2[0];
    o[4] = p2[1]; o[5] = p3[0]; o[6] = p3[1]; o[7] = o7;
    if (EDGE) {
#pragma unroll
        for (int r = 0; r < 8; ++r) {
            const bool ok = ((unsigned)(gpos + r) < (unsigned)Nlev);
            o[r] = ok ? o[r] : 0.f;
        }
    }
}

// Compute+store for one synthesis task (inputs already in registers).
template<int Sout, int Nlev, bool EDGE>
__device__ __forceinline__ void synth_cs(
    const float* __restrict__ ya, const float* __restrict__ yb, int g, int nl0,
    float* __restrict__ out, const f2* __restrict__ lrev, const f2* __restrict__ hrev,
    int outBase)
{
    float o[8];
    synth_core<0, EDGE>(ya, yb, lrev, hrev, outBase + nl0, Nlev, o);
    float* op = out + g * Sout + nl0;
    stf4(op,     make_float4(o[0], o[1], o[2], o[3]));
    stf4(op + 4, make_float4(o[4], o[5], o[6], o[7]));
}

// Dual-task block-wide synthesis + small guarded tail (TOT in [2*TPB+2, 3*TPB]).
template<int INSTRIDE, int Sout, int G, int Nlev, bool EDGE>
__device__ __forceinline__ void synthN(
    const float* __restrict__ in, float* __restrict__ out,
    const f2* __restrict__ lrev, const f2* __restrict__ hrev, int outBase)
{
    constexpr int TPG = Sout / 8;
    constexpr int TOT = G * TPG;
    static_assert(TOT >= 2 * TPB && TOT <= 3 * TPB, "synth: two full + tail");
    const int t0 = threadIdx.x;
    const int t1 = t0 + TPB;                 // TOT >= 512+2 -> unconditional
    const int g0 = t0 / TPG, nl00 = (t0 - g0 * TPG) * 8;
    const int g1 = t1 / TPG, nl01 = (t1 - g1 * TPG) * 8;

    float ya0[8], yb0[8], ya1[8], yb1[8];
    {
        const int sw = g0 & 1;
        ld8(ya0, in + (2 * g0 + sw)     * INSTRIDE + nl00 / 2);
        ld8(yb0, in + (2 * g0 + 1 - sw) * INSTRIDE + nl00 / 2);
    }
    {
        const int sw = g1 & 1;
        ld8(ya1, in + (2 * g1 + sw)     * INSTRIDE + nl01 / 2);
        ld8(yb1, in + (2 * g1 + 1 - sw) * INSTRIDE + nl01 / 2);
    }
    synth_cs<Sout, Nlev, EDGE>(ya0, yb0, g0, nl00, out, lrev, hrev, outBase);
    synth_cs<Sout, Nlev, EDGE>(ya1, yb1, g1, nl01, out, lrev, hrev, outBase);

    const int t2 = t0 + 2 * TPB;             // tail: 2..16 threads
    if (t2 < TOT) {
        const int g2 = t2 / TPG, nl02 = (t2 - g2 * TPG) * 8;
        const int sw = g2 & 1;
        float ya2[8], yb2[8];
        ld8(ya2, in + (2 * g2 + sw)     * INSTRIDE + nl02 / 2);
        ld8(yb2, in + (2 * g2 + 1 - sw) * INSTRIDE + nl02 / 2);
        synth_cs<Sout, Nlev, EDGE>(ya2, yb2, g2, nl02, out, lrev, hrev, outBase);
    }
}

template<bool EDGE>
__device__ __forceinline__ void run_chunk(
    const float* __restrict__ xb, float* __restrict__ ob, int s,
    float* __restrict__ bufA, float* __restrict__ bufB,
    const f2* __restrict__ klh, const f2* __restrict__ lrev, const f2* __restrict__ hrev,
    const float* __restrict__ bss)
{
    const int tid = threadIdx.x;

    // ---- L1 directly from global (dual-task, 287 tasks); no stage phase ----
    {
        const int t1 = tid + TPB;
        const bool has1 = (t1 < 287);
        float w0[28], w1[28];
        l1_ld<EDGE>(xb, s, tid, w0);
        if (has1) l1_ld<EDGE>(xb, s, t1, w1);
        l1_do<EDGE>(w0, tid, bufB, klh, bss, s);
        if (has1) l1_do<EDGE>(w1, t1, bufB, klh, bss, s);
    }
    __syncthreads();

    // ---- analysis L2..L5 (dual-task from LDS); task counts 286,284,280,272 ----
    analysis8<1148, 1144,  2,  8192, EDGE, 1144,  572>(bufB, bufA, klh, bss + 2,  (s >> 2) - 53);
    __syncthreads();
    analysis8< 572,  568,  4,  4096, EDGE,  568,  284>(bufA, bufB, klh, bss + 6,  (s >> 3) - 25);
    __syncthreads();
    analysis8< 284,  280,  8,  2048, EDGE,  280,  140>(bufB, bufA, klh, bss + 14, (s >> 4) - 11);
    __syncthreads();
    analysis8< 140,  136, 16,  1024, EDGE,  136,    0, true>(bufA, bufB, klh, bss + 30, (s >> 5) - 4);
    __syncthreads();

    // ---- synthesis s5..s2 (dual-task + tail); task counts 528,520,516,514 ----
    synthN< 136,  264, 16,  2048, EDGE>(bufB, bufA, lrev, hrev, (s >> 4) - 4);   // L5 -> r4
    __syncthreads();
    synthN< 264,  520,  8,  4096, EDGE>(bufA, bufB, lrev, hrev, (s >> 3) - 4);   // r4 -> r3
    __syncthreads();
    synthN< 520, 1032,  4,  8192, EDGE>(bufB, bufA, lrev, hrev, (s >> 2) - 4);   // r3 -> r2
    __syncthreads();
    synthN<1032, 2056,  2, 16384, EDGE>(bufA, bufB, lrev, hrev, (s >> 1) - 4);   // r2 -> r1
    __syncthreads();

    // ---- final level (G=1) to global; r1 in bufB stride 2056; 512 tasks x 8, dual ----
    {
#pragma unroll
        for (int k = 0; k < 2; ++k) {
            const int t  = tid + TPB * k;
            const int i0 = t * 8;
            float ya[12], yb[12];
            const float* p0 = bufB + i0 / 2;          // channel 0 = lp (16B aligned)
            ld12(ya, p0);
            ld12(yb, p0 + 2056);
            float o[8];
            synth_core<2, false>(ya, yb, lrev, hrev, 0, 1 << 30, o);
            stf4(ob + i0,     make_float4(o[0], o[1], o[2], o[3]));
            stf4(ob + i0 + 4, make_float4(o[4], o[5], o[6], o[7]));
        }
    }
}

__global__ __launch_bounds__(TPB, 4) void wpt_fused(
    const float* __restrict__ x,
    const float* __restrict__ K1, const float* __restrict__ K2,
    const float* __restrict__ K3, const float* __restrict__ K4,
    const float* __restrict__ K5,
    const float* __restrict__ B1, const float* __restrict__ B2,
    const float* __restrict__ B3, const float* __restrict__ B4,
    const float* __restrict__ B5,
    float* __restrict__ out)
{
    __shared__ __align__(16) float bufA[4608];
    __shared__ __align__(16) float bufB[4608];
    __shared__ float bss[62];

    const int tid   = threadIdx.x;
    const int batch = blockIdx.x >> 3;
    const int cid   = blockIdx.x & 7;
    const int s     = cid * C0;

    // Filters in SGPRs: K1 = [lp | hp]; every level's rows are one of these two.
    float lp[8], hp[8];
#pragma unroll
    for (int t = 0; t < 8; ++t) {
        lp[t] = rfl(K1[t]);
        hp[t] = rfl(K1[8 + t]);
    }
    // Packed coefficient tables for pk_fma paths.
    f2 klh[8], lrev[4], hrev[4];
#pragma unroll
    for (int t = 0; t < 8; ++t) klh[t] = (f2){lp[t], hp[t]};
#pragma unroll
    for (int q = 0; q < 4; ++q) {
        lrev[q] = (f2){lp[6 - 2 * q], lp[7 - 2 * q]};
        hrev[q] = (f2){hp[6 - 2 * q], hp[7 - 2 * q]};
    }

    // Biases (pre-scaled by 10*log2(e)); 62 total. Barrier: L1 reads bss.
    {
        const float* bin[5] = {B1, B2, B3, B4, B5};
        const int boff[5] = {0, 2, 6, 14, 30};
#pragma unroll
        for (int l = 0; l < 5; ++l)
            for (int i = tid; i < (2 << l); i += TPB) bss[boff[l] + i] = SCG * bin[l][i];
    }
    __syncthreads();

    const float* xb = x + batch * NSEQ;
    float* ob = out + batch * NSEQ + s;

    if (cid == 0 || cid == 7)
        run_chunk<true >(xb, ob, s, bufA, bufB, klh, lrev, hrev, bss);
    else
        run_chunk<false>(xb, ob, s, bufA, bufB, klh, lrev, hrev, bss);
}

extern "C" void kernel_launch(void* const* d_in, const int* in_sizes, int n_in,
                              void* d_out, int out_size, void* d_ws, size_t ws_size,
                              hipStream_t stream) {
    const int nbatch = in_sizes[0] / NSEQ;
    wpt_fused<<<dim3(nbatch * (NSEQ / C0)), dim3(TPB), 0, stream>>>(
        (const float*)d_in[0],
        (const float*)d_in[1], (const float*)d_in[2],
        (const float*)d_in[3], (const float*)d_in[4],
        (const float*)d_in[5],
        (const float*)d_in[6], (const float*)d_in[7],
        (const float*)d_in[8], (const float*)d_in[9],
        (const float*)d_in[10],
        (float*)d_out);
}

// Round 10
// 111.845 us; speedup vs baseline: 1.0523x; 1.0287x over previous
//
#include <hip/hip_runtime.h>

#define TPB 256

constexpr int NSEQ = 32768;
constexpr int C0   = 4096;               // output samples per block chunk (8 chunks/batch)
constexpr float SCG = 14.4269504089f;    // 10 * log2(e)

// Halos h_l = 2*h_{l+1}+3, h5=4 -> {221,109,53,25,11,4}
// Geometry: P5 = C0/32 + 8, P_{l-1} = 2*P_l + 8.
// C0=4096 padded level widths P: {2296,1144,568,280,136}; E/O halves {1148,572,284,140};
// L5 out contiguous stride 136; synthesis Sout {264,520,1032,2056}; final 4096.
//
// R10 = R7 (best, bench 111.1) + BLOCK START STAGGER. Hypothesis under test:
// co-resident blocks stay phase-LOCKED (identical barrier-phased structure,
// simultaneous dispatch), so all waves on a CU burst LDS together then VALU
// together -> wall ~ LDS+VALU (sum). Staggering co-resident blocks by ~quarter
// phase-period (~512cy steps, via s_sleep) anti-phases them -> one block's LDS
// burst overlaps another's VALU burst -> wall -> max(). Cost if wrong: <=1.5K cy.
//
// R7 structure: TPB=256, DUAL-TASK phases (thread handles tid, tid+256[, tid+512]).
// 10 barriers: stage|L1|L2|L3|L4|L5|s5|s4|s3|s2|final.
// Ping-pong: stage->A, L1 A->B, L2 B->A, L3 A->B, L4 B->A, L5 A->B,
//            s5 B->A, s4 A->B, s3 B->A, s2 A->B, final B->global.
// LDS = (4608+4608+62)*4 = 37112 B -> 4 blocks/CU; 4 waves/block -> 16 waves/CU.
// Grid = 128 batches * 8 chunks = 1024 blocks = 4 * 256 CUs.

typedef float f2 __attribute__((ext_vector_type(2)));

__device__ __forceinline__ f2 sp(float x) { return (f2){x, x}; }
__device__ __forceinline__ f2 fma2(f2 a, f2 b, f2 c) { return __builtin_elementwise_fma(a, b, c); }

__device__ __forceinline__ float4 ldf4(const float* p) { return *reinterpret_cast<const float4*>(p); }
__device__ __forceinline__ void   stf4(float* p, const float4 v) { *reinterpret_cast<float4*>(p) = v; }

__device__ __forceinline__ void ld12(float* d, const float* p) {
    reinterpret_cast<float4*>(d)[0] = ldf4(p);
    reinterpret_cast<float4*>(d)[1] = ldf4(p + 4);
    reinterpret_cast<float4*>(d)[2] = ldf4(p + 8);
}
__device__ __forceinline__ void ld8(float* d, const float* p) {
    reinterpret_cast<float4*>(d)[0] = ldf4(p);
    reinterpret_cast<float4*>(d)[1] = ldf4(p + 4);
}

__device__ __forceinline__ float rfl(float x) {
    return __builtin_bit_cast(float, __builtin_amdgcn_readfirstlane(__builtin_bit_cast(int, x)));
}

// Packed gate: y * (sigmoid(10(y-b)) + sigmoid(-10(y+b))) on both halves; tb = SCG*b.
__device__ __forceinline__ f2 gated2(f2 y, f2 tb) {
    f2 t1 = fma2(y, sp(-SCG), tb);
    f2 t2 = fma2(y, sp( SCG), tb);
    f2 s;
    s[0] = __builtin_amdgcn_rcpf(1.f + __builtin_amdgcn_exp2f(t1[0]))
         + __builtin_amdgcn_rcpf(1.f + __builtin_amdgcn_exp2f(t2[0]));
    s[1] = __builtin_amdgcn_rcpf(1.f + __builtin_amdgcn_exp2f(t1[1]))
         + __builtin_amdgcn_rcpf(1.f + __builtin_amdgcn_exp2f(t2[1]));
    return y * s;
}

// Compute+store for one analysis task (inputs already in registers).
template<int Nlev, bool EDGE, int OUTSTRIDE, int EOOFF, bool LAST>
__device__ __forceinline__ void analysis_cs(
    const float* __restrict__ a, const float* __restrict__ b, int c, int i0,
    float* __restrict__ out, const f2* __restrict__ klh,
    const float* __restrict__ bias, int outBase)
{
    const int sw    = c & 1;
    const int ch_lp = 2 * c + sw;
    const int ch_hp = 2 * c + 1 - sw;
    const f2  tb    = (f2){bias[ch_lp], bias[ch_hp]};

    if (LAST) {
        f2 v[8];
#pragma unroll
        for (int r = 0; r < 8; ++r) {
            f2 y = (f2){0.f, 0.f};
#pragma unroll
            for (int u = 0; u < 4; ++u) {
                y = fma2(sp(a[r + u]), klh[2 * u], y);
                y = fma2(sp(b[r + u]), klh[2 * u + 1], y);
            }
            y = gated2(y, tb);
            if (EDGE) {
                const bool ok = ((unsigned)(outBase + i0 + r) < (unsigned)Nlev);
                y[0] = ok ? y[0] : 0.f;
                y[1] = ok ? y[1] : 0.f;
            }
            v[r] = y;
        }
        float* ol = out + ch_lp * OUTSTRIDE + i0;
        float* oh = out + ch_hp * OUTSTRIDE + i0;
        stf4(ol,     make_float4(v[0][0], v[1][0], v[2][0], v[3][0]));
        stf4(ol + 4, make_float4(v[4][0], v[5][0], v[6][0], v[7][0]));
        stf4(oh,     make_float4(v[0][1], v[1][1], v[2][1], v[3][1]));
        stf4(oh + 4, make_float4(v[4][1], v[5][1], v[6][1], v[7][1]));
    } else {
        const int j0 = i0 >> 1;
        float* ol = out + ch_lp * OUTSTRIDE + j0;
        float* oh = out + ch_hp * OUTSTRIDE + j0;
#pragma unroll
        for (int par = 0; par < 2; ++par) {            // par=0 -> E plane, par=1 -> O plane
            f2 w[4];
#pragma unroll
            for (int k = 0; k < 4; ++k) {
                const int r = 2 * k + par;
                f2 y = (f2){0.f, 0.f};
#pragma unroll
                for (int u = 0; u < 4; ++u) {
                    y = fma2(sp(a[r + u]), klh[2 * u], y);
                    y = fma2(sp(b[r + u]), klh[2 * u + 1], y);
                }
                y = gated2(y, tb);
                if (EDGE) {
                    const bool ok = ((unsigned)(outBase + i0 + r) < (unsigned)Nlev);
                    y[0] = ok ? y[0] : 0.f;
                    y[1] = ok ? y[1] : 0.f;
                }
                w[k] = y;
            }
            stf4(ol + par * EOOFF, make_float4(w[0][0], w[1][0], w[2][0], w[3][0]));
            stf4(oh + par * EOOFF, make_float4(w[0][1], w[1][1], w[2][1], w[3][1]));
        }
    }
}

// Dual-task block-wide analysis (TOT in (TPB, 2*TPB]); loads for BOTH tasks
// issued before either compute.
template<int LEin, int P, int PAIRS, int Nlev, bool EDGE, int OUTSTRIDE, int EOOFF, bool LAST = false>
__device__ __forceinline__ void analysis8(
    const float* __restrict__ in, float* __restrict__ out,
    const f2* __restrict__ klh, const float* __restrict__ bias, int outBase)
{
    constexpr int TPC = P / 8;
    constexpr int TOT = PAIRS * TPC;
    static_assert(TOT > TPB && TOT <= 2 * TPB, "analysis must be dual-generation");
    const int t0 = threadIdx.x;
    const int t1 = t0 + TPB;
    const bool has1 = (t1 < TOT);

    const int c0 = t0 / TPC, i0 = (t0 - c0 * TPC) * 8;
    const int c1 = t1 / TPC, i1 = (t1 - c1 * TPC) * 8;

    float a0[12], b0[12], a1[12], b1[12];
    {
        const float* pe = in + c0 * (2 * LEin) + i0;
        ld12(a0, pe);
        ld12(b0, pe + LEin);
    }
    if (has1) {
        const float* pe = in + c1 * (2 * LEin) + i1;
        ld12(a1, pe);
        ld12(b1, pe + LEin);
    }
    analysis_cs<Nlev, EDGE, OUTSTRIDE, EOOFF, LAST>(a0, b0, c0, i0, out, klh, bias, outBase);
    if (has1)
        analysis_cs<Nlev, EDGE, OUTSTRIDE, EOOFF, LAST>(a1, b1, c1, i1, out, klh, bias, outBase);
}

// Packed synthesis core: 8 outputs from ya/yb windows.
// lrev[q] = (lp[6-2q], lp[7-2q]); hrev[q] = (hp[6-2q], hp[7-2q]).  JROFF: window offset.
template<int JROFF, bool EDGE>
__device__ __forceinline__ void synth_core(
    const float* __restrict__ ya, const float* __restrict__ yb,
    const f2* __restrict__ lrev, const f2* __restrict__ hrev,
    int gpos, int Nlev, float* __restrict__ o)
{
    f2 p1 = (f2){0.f, 0.f}, p2 = (f2){0.f, 0.f}, p3 = (f2){0.f, 0.f};
    float o0 = 0.f, o7 = 0.f;
#pragma unroll
    for (int q = 0; q < 4; ++q) {
        const f2 cl = lrev[q], ch = hrev[q];
        o0 = fmaf(ya[JROFF + q],     cl[1], o0);
        o0 = fmaf(yb[JROFF + q],     ch[1], o0);
        o7 = fmaf(ya[JROFF + 4 + q], cl[0], o7);
        o7 = fmaf(yb[JROFF + 4 + q], ch[0], o7);
        p1 = fma2(sp(ya[JROFF + 1 + q]), cl, p1);
        p1 = fma2(sp(yb[JROFF + 1 + q]), ch, p1);
        p2 = fma2(sp(ya[JROFF + 2 + q]), cl, p2);
        p2 = fma2(sp(yb[JROFF + 2 + q]), ch, p2);
        p3 = fma2(sp(ya[JROFF + 3 + q]), cl, p3);
        p3 = fma2(sp(yb[JROFF + 3 + q]), ch, p3);
    }
    o[0] = o0;    o[1] = p1[0]; o[2] = p1[1]; o[3] = p2[0];
    o[4] = p2[1]; o[5] = p3[0]; o[6] = p3[1]; o[7] = o7;
    if (EDGE) {
#pragma unroll
        for (int r = 0; r < 8; ++r) {
            const bool ok = ((unsigned)(gpos + r) < (unsigned)Nlev);
            o[r] = ok ? o[r] : 0.f;
        }
    }
}

// Compute+store for one synthesis task (inputs already in registers).
template<int Sout, int Nlev, bool EDGE>
__device__ __forceinline__ void synth_cs(
    const float* __restrict__ ya, const float* __restrict__ yb, int g, int nl0,
    float* __restrict__ out, const f2* __restrict__ lrev, const f2* __restrict__ hrev,
    int outBase)
{
    float o[8];
    synth_core<0, EDGE>(ya, yb, lrev, hrev, outBase + nl0, Nlev, o);
    float* op = out + g * Sout + nl0;
    stf4(op,     make_float4(o[0], o[1], o[2], o[3]));
    stf4(op + 4, make_float4(o[4], o[5], o[6], o[7]));
}

// Dual-task block-wide synthesis + small guarded tail (TOT in [2*TPB+2, 3*TPB]).
template<int INSTRIDE, int Sout, int G, int Nlev, bool EDGE>
__device__ __forceinline__ void synthN(
    const float* __restrict__ in, float* __restrict__ out,
    const f2* __restrict__ lrev, const f2* __restrict__ hrev, int outBase)
{
    constexpr int TPG = Sout / 8;
    constexpr int TOT = G * TPG;
    static_assert(TOT >= 2 * TPB && TOT <= 3 * TPB, "synth: two full + tail");
    const int t0 = threadIdx.x;
    const int t1 = t0 + TPB;                 // TOT >= 512+2 -> unconditional
    const int g0 = t0 / TPG, nl00 = (t0 - g0 * TPG) * 8;
    const int g1 = t1 / TPG, nl01 = (t1 - g1 * TPG) * 8;

    float ya0[8], yb0[8], ya1[8], yb1[8];
    {
        const int sw = g0 & 1;
        ld8(ya0, in + (2 * g0 + sw)     * INSTRIDE + nl00 / 2);
        ld8(yb0, in + (2 * g0 + 1 - sw) * INSTRIDE + nl00 / 2);
    }
    {
        const int sw = g1 & 1;
        ld8(ya1, in + (2 * g1 + sw)     * INSTRIDE + nl01 / 2);
        ld8(yb1, in + (2 * g1 + 1 - sw) * INSTRIDE + nl01 / 2);
    }
    synth_cs<Sout, Nlev, EDGE>(ya0, yb0, g0, nl00, out, lrev, hrev, outBase);
    synth_cs<Sout, Nlev, EDGE>(ya1, yb1, g1, nl01, out, lrev, hrev, outBase);

    const int t2 = t0 + 2 * TPB;             // tail: 2..16 threads
    if (t2 < TOT) {
        const int g2 = t2 / TPG, nl02 = (t2 - g2 * TPG) * 8;
        const int sw = g2 & 1;
        float ya2[8], yb2[8];
        ld8(ya2, in + (2 * g2 + sw)     * INSTRIDE + nl02 / 2);
        ld8(yb2, in + (2 * g2 + 1 - sw) * INSTRIDE + nl02 / 2);
        synth_cs<Sout, Nlev, EDGE>(ya2, yb2, g2, nl02, out, lrev, hrev, outBase);
    }
}

template<bool EDGE>
__device__ __forceinline__ void run_chunk(
    const float* __restrict__ xb, float* __restrict__ ob, int s,
    float* __restrict__ bufA, float* __restrict__ bufB,
    const f2* __restrict__ klh, const f2* __restrict__ lrev, const f2* __restrict__ hrev,
    const float* __restrict__ bss)
{
    const int tid = threadIdx.x;

    // Stage: aligned float4 global loads, deinterleaved to E@0 / O@2304.
    // base = s-221 (== 3 mod 4), a0 = base-3 (16B aligned).  Quad q covers
    // x[a0+4q .. a0+4q+3] -> O[2q-2], E[2q-1], O[2q-1], E[2q]  (edge-guarded).
    {
        const int base = s - 221;
        const int a0   = base - 3;
#pragma unroll
        for (int k = 0; k < 5; ++k) {
            const int q = tid + TPB * k;
            if (q < 1151) {
                const int a = a0 + 4 * q;
                float4 v;
                if (!EDGE || (a >= 0 && a + 3 < NSEQ)) {
                    v = ldf4(xb + a);
                } else {
                    v.x = ((unsigned)(a)     < (unsigned)NSEQ) ? xb[a]     : 0.f;
                    v.y = ((unsigned)(a + 1) < (unsigned)NSEQ) ? xb[a + 1] : 0.f;
                    v.z = ((unsigned)(a + 2) < (unsigned)NSEQ) ? xb[a + 2] : 0.f;
                    v.w = ((unsigned)(a + 3) < (unsigned)NSEQ) ? xb[a + 3] : 0.f;
                }
                const int jo = 2 * q - 2;
                const int je = 2 * q - 1;
                if ((unsigned)jo       < 2300u) bufA[2304 + jo]     = v.x;  // O[2q-2]
                if ((unsigned)je       < 2300u) bufA[je]            = v.y;  // E[2q-1]
                if ((unsigned)(jo + 1) < 2300u) bufA[2304 + jo + 1] = v.z;  // O[2q-1]
                if ((unsigned)(je + 1) < 2300u) bufA[je + 1]        = v.w;  // E[2q]
            }
        }
    }
    __syncthreads();

    // ---- analysis L1..L5 (dual-task); task counts 287,286,284,280,272 ----
    analysis8<2304, 2296,  1, 16384, EDGE, 2296, 1148>(bufA, bufB, klh, bss + 0,  (s >> 1) - 109);
    __syncthreads();
    analysis8<1148, 1144,  2,  8192, EDGE, 1144,  572>(bufB, bufA, klh, bss + 2,  (s >> 2) - 53);
    __syncthreads();
    analysis8< 572,  568,  4,  4096, EDGE,  568,  284>(bufA, bufB, klh, bss + 6,  (s >> 3) - 25);
    __syncthreads();
    analysis8< 284,  280,  8,  2048, EDGE,  280,  140>(bufB, bufA, klh, bss + 14, (s >> 4) - 11);
    __syncthreads();
    analysis8< 140,  136, 16,  1024, EDGE,  136,    0, true>(bufA, bufB, klh, bss + 30, (s >> 5) - 4);
    __syncthreads();

    // ---- synthesis s5..s2 (dual-task + tail); task counts 528,520,516,514 ----
    synthN< 136,  264, 16,  2048, EDGE>(bufB, bufA, lrev, hrev, (s >> 4) - 4);   // L5 -> r4
    __syncthreads();
    synthN< 264,  520,  8,  4096, EDGE>(bufA, bufB, lrev, hrev, (s >> 3) - 4);   // r4 -> r3
    __syncthreads();
    synthN< 520, 1032,  4,  8192, EDGE>(bufB, bufA, lrev, hrev, (s >> 2) - 4);   // r3 -> r2
    __syncthreads();
    synthN<1032, 2056,  2, 16384, EDGE>(bufA, bufB, lrev, hrev, (s >> 1) - 4);   // r2 -> r1
    __syncthreads();

    // ---- final level (G=1) to global; r1 in bufB stride 2056; 512 tasks x 8, dual ----
    {
#pragma unroll
        for (int k = 0; k < 2; ++k) {
            const int t  = tid + TPB * k;
            const int i0 = t * 8;
            float ya[12], yb[12];
            const float* p0 = bufB + i0 / 2;          // channel 0 = lp (16B aligned)
            ld12(ya, p0);
            ld12(yb, p0 + 2056);
            float o[8];
            synth_core<2, false>(ya, yb, lrev, hrev, 0, 1 << 30, o);
            stf4(ob + i0,     make_float4(o[0], o[1], o[2], o[3]));
            stf4(ob + i0 + 4, make_float4(o[4], o[5], o[6], o[7]));
        }
    }
}

__global__ __launch_bounds__(TPB, 4) void wpt_fused(
    const float* __restrict__ x,
    const float* __restrict__ K1, const float* __restrict__ K2,
    const float* __restrict__ K3, const float* __restrict__ K4,
    const float* __restrict__ K5,
    const float* __restrict__ B1, const float* __restrict__ B2,
    const float* __restrict__ B3, const float* __restrict__ B4,
    const float* __restrict__ B5,
    float* __restrict__ out)
{
    __shared__ __align__(16) float bufA[4608];
    __shared__ __align__(16) float bufB[4608];
    __shared__ float bss[62];

    const int tid   = threadIdx.x;
    const int batch = blockIdx.x >> 3;
    const int cid   = blockIdx.x & 7;
    const int s     = cid * C0;

    // ---- start stagger: anti-phase co-resident blocks (generation = bid>>8
    // under round-robin CU fill). Each s_sleep(8) ~ 512 cycles; phase period
    // ~2.3K cycles -> offsets 0 / 0.5K / 1K / 1.5K ~ quarter-period steps. ----
    switch ((blockIdx.x >> 8) & 3) {
        case 1: __builtin_amdgcn_s_sleep(8); break;
        case 2: __builtin_amdgcn_s_sleep(8); __builtin_amdgcn_s_sleep(8); break;
        case 3: __builtin_amdgcn_s_sleep(8); __builtin_amdgcn_s_sleep(8);
                __builtin_amdgcn_s_sleep(8); break;
        default: break;
    }

    // Filters in SGPRs: K1 = [lp | hp]; every level's rows are one of these two.
    float lp[8], hp[8];
#pragma unroll
    for (int t = 0; t < 8; ++t) {
        lp[t] = rfl(K1[t]);
        hp[t] = rfl(K1[8 + t]);
    }
    // Packed coefficient tables for pk_fma paths.
    f2 klh[8], lrev[4], hrev[4];
#pragma unroll
    for (int t = 0; t < 8; ++t) klh[t] = (f2){lp[t], hp[t]};
#pragma unroll
    for (int q = 0; q < 4; ++q) {
        lrev[q] = (f2){lp[6 - 2 * q], lp[7 - 2 * q]};
        hrev[q] = (f2){hp[6 - 2 * q], hp[7 - 2 * q]};
    }

    // Biases (pre-scaled by 10*log2(e)); 62 total
    {
        const float* bin[5] = {B1, B2, B3, B4, B5};
        const int boff[5] = {0, 2, 6, 14, 30};
#pragma unroll
        for (int l = 0; l < 5; ++l)
            for (int i = tid; i < (2 << l); i += TPB) bss[boff[l] + i] = SCG * bin[l][i];
    }

    const float* xb = x + batch * NSEQ;
    float* ob = out + batch * NSEQ + s;

    if (cid == 0 || cid == 7)
        run_chunk<true >(xb, ob, s, bufA, bufB, klh, lrev, hrev, bss);
    else
        run_chunk<false>(xb, ob, s, bufA, bufB, klh, lrev, hrev, bss);
}

extern "C" void kernel_launch(void* const* d_in, const int* in_sizes, int n_in,
                              void* d_out, int out_size, void* d_ws, size_t ws_size,
                              hipStream_t stream) {
    const int nbatch = in_sizes[0] / NSEQ;
    wpt_fused<<<dim3(nbatch * (NSEQ / C0)), dim3(TPB), 0, stream>>>(
        (const float*)d_in[0],
        (const float*)d_in[1], (const float*)d_in[2],
        (const float*)d_in[3], (const float*)d_in[4],
        (const float*)d_in[5],
        (const float*)d_in[6], (const float*)d_in[7],
        (const float*)d_in[8], (const float*)d_in[9],
        (const float*)d_in[10],
        (float*)d_out);
}